// Round 5
// baseline (538.301 us; speedup 1.0000x reference)
//
#include <hip/hip_runtime.h>
#include <hip/hip_bf16.h>

// EncoderCell, bf16-MFMA, round 5.
//   gemm_bf16: 128x128 tile, m97-style gl_lds16 staging; lda/ldb + split-K via z.
//   attn_mfma: S^T = K.Q^T; XOR-chunk-swizzled gl_lds16 staging, DOUBLE-BUFFERED
//              K/V (prefetch tile kt+1 before compute(kt), 1 barrier/iter);
//              mask pre-scaled by log2e -> bare v_exp_f32; P packed by trunc v_perm.
//   ln_res:    mode 0: out=LN(a+a2)+r ; mode 1: out=LN(a+a2+r). a2 nullable.
// ws (MiB): [0,24) qb|kb|vb -> vhT|zb|xb ; [24,32) WqT|WkT|WvT|WdT ; [32,40) W1T ;
//   [40,48) W2T ; [48,72) qh|kh|vh ; zd0 [48,64), zd1 [64,80) ; x [80,96) ;
//   h1 [96,128) (maskl2e borrows [96,112) during attention).  = 128 MiB.

#define SEQ 2048
#define DM  1024
#define LNEPS 1e-5f
#define SCL  0.1803368801f   // 0.125 * log2(e)

typedef __attribute__((ext_vector_type(8))) short bf16x8;
typedef __attribute__((ext_vector_type(4))) float f32x4;

#define GAS __attribute__((address_space(1)))
#define LAS __attribute__((address_space(3)))

static __device__ __forceinline__ void gl_lds16(const unsigned short* g, unsigned short* l) {
    __builtin_amdgcn_global_load_lds((const GAS void*)g, (LAS void*)l, 16, 0, 0);
}

static __device__ __forceinline__ unsigned short f2bf(float f) {
    unsigned u = __builtin_bit_cast(unsigned, f);
    u += 0x7fffu + ((u >> 16) & 1u);   // RNE
    return (unsigned short)(u >> 16);
}

// pack two fp32 -> two bf16 (truncation) in one v_perm_b32
static __device__ __forceinline__ unsigned pack_bf16_trunc(float a, float b) {
    return __builtin_amdgcn_perm(__builtin_bit_cast(unsigned, b),
                                 __builtin_bit_cast(unsigned, a), 0x07060302u);
}

// ------------------------------------------------------------------
// C[M,N] (per-z slice) = A[M,Klen] @ Bt[N,Klen]^T. bias only on z==0.
// ------------------------------------------------------------------
__global__ __launch_bounds__(256) void gemm_bf16(
    const unsigned short* __restrict__ A, const unsigned short* __restrict__ Bt,
    float* __restrict__ Cf, unsigned short* __restrict__ Cb,
    int M, int N, int Klen, int lda, int ldb,
    size_t sA, size_t sB, size_t sC,
    const float* __restrict__ bias, int ep)
{
    __shared__ unsigned short As[128 * 32];
    __shared__ unsigned short Bs[128 * 32];

    const int t = threadIdx.x, lane = t & 63, w = t >> 6;
    const int wm = w >> 1, wn = w & 1;
    const int m0 = blockIdx.y * 128, n0 = blockIdx.x * 128;
    A  += (size_t)blockIdx.z * sA;
    Bt += (size_t)blockIdx.z * sB;
    const size_t cbase = (size_t)blockIdx.z * sC;
    const int l15 = lane & 15, l16 = lane >> 4;
    const int ar = lane >> 2, ac = (lane & 3) * 8;

    f32x4 acc[4][4];
    #pragma unroll
    for (int i = 0; i < 4; i++)
        #pragma unroll
        for (int j = 0; j < 4; j++)
            acc[i][j] = (f32x4){0.f, 0.f, 0.f, 0.f};

    for (int k0 = 0; k0 < Klen; k0 += 32) {
        __syncthreads();
        #pragma unroll
        for (int i = 0; i < 2; i++) {
            const int rg = w * 2 + i;
            gl_lds16(&A [(size_t)(m0 + rg * 16 + ar) * lda + k0 + ac], &As[rg * 512]);
            gl_lds16(&Bt[(size_t)(n0 + rg * 16 + ar) * ldb + k0 + ac], &Bs[rg * 512]);
        }
        __syncthreads();

        bf16x8 af[4], bfr[4];
        #pragma unroll
        for (int i = 0; i < 4; i++) {
            af[i]  = *(const bf16x8*)&As[(wm * 64 + i * 16 + l15) * 32 + l16 * 8];
            bfr[i] = *(const bf16x8*)&Bs[(wn * 64 + i * 16 + l15) * 32 + l16 * 8];
        }
        #pragma unroll
        for (int mi = 0; mi < 4; mi++)
            #pragma unroll
            for (int ni = 0; ni < 4; ni++)
                acc[mi][ni] = __builtin_amdgcn_mfma_f32_16x16x32_bf16(
                    af[mi], bfr[ni], acc[mi][ni], 0, 0, 0);
    }

    #pragma unroll
    for (int ni = 0; ni < 4; ni++) {
        const int col = n0 + wn * 64 + ni * 16 + l15;
        const float bv = (ep && blockIdx.z == 0) ? bias[col] : 0.f;
        #pragma unroll
        for (int mi = 0; mi < 4; mi++) {
            #pragma unroll
            for (int r = 0; r < 4; r++) {
                const int row = m0 + wm * 64 + mi * 16 + l16 * 4 + r;
                float vv = acc[mi][ni][r] + bv;
                if (ep == 2) vv = fmaxf(vv, 0.f);
                if (Cf) Cf[cbase + (size_t)row * N + col] = vv;
                else    Cb[cbase + (size_t)row * N + col] = f2bf(vv);
            }
        }
    }
}

// ------------------------------------------------------------------
// Flash attention, S^T formulation, double-buffered gl_lds16 staging.
// grid = 1024; qt=bid>>5 (mask L2 reuse), h=bid&15, b=(bid>>4)&1.
// Wave w owns q rows [w*16, w*16+16); lane owns q-row qr+l15.
// maskl = mask * log2(e); scores scaled by 0.125*log2(e) -> p = exp2(sv-mnew).
// ------------------------------------------------------------------
__global__ __launch_bounds__(256) void attn_mfma(
    const unsigned short* __restrict__ qh, const unsigned short* __restrict__ kh,
    const unsigned short* __restrict__ vhT, const float* __restrict__ maskl,
    unsigned short* __restrict__ z)
{
    __shared__ unsigned short Qs[64 * 64];       // swizzled [row][chunk^(row&7)]
    __shared__ unsigned short Ks[2][64 * 64];    // swizzled, [key][d], double-buffered
    __shared__ unsigned short Vst[2][64 * 64];   // swizzled, [d][key], double-buffered
    __shared__ unsigned short Ps[64 * 72];       // [q][key], stride 72

    const int t = threadIdx.x, lane = t & 63, w = t >> 6;
    const int bid = blockIdx.x;
    const int qt = bid >> 5, h = bid & 15, b = (bid >> 4) & 1;
    const int q0 = qt * 64, qr = w * 16;
    const int l15 = lane & 15, l16 = lane >> 4;

    const int lr = lane >> 3;
    const int gc = ((lane & 7) ^ lr) * 8;        // swizzled source chunk (shorts)

    const size_t qbase = (size_t)(b * SEQ + q0) * DM + h * 64;
    const size_t kbase = (size_t)(b * SEQ) * DM + h * 64;
    const size_t vbase = (size_t)((b * 16 + h) * 64) * SEQ;

    // stage Q + tile 0 K/V (buffer 0)
    #pragma unroll
    for (int i = 0; i < 2; i++) {
        const int rg = w * 2 + i;
        gl_lds16(&qh [qbase + (size_t)(rg * 8 + lr) * DM + gc], &Qs[rg * 512]);
        gl_lds16(&kh [kbase + (size_t)(rg * 8 + lr) * DM + gc], &Ks[0][rg * 512]);
        gl_lds16(&vhT[vbase + (size_t)(rg * 8 + lr) * SEQ + gc], &Vst[0][rg * 512]);
    }
    __syncthreads();

    const int sw0 = ((l16    ) ^ (l15 & 7)) * 8;
    const int sw1 = ((l16 + 4) ^ (l15 & 7)) * 8;
    const bf16x8 bQ0 = *(const bf16x8*)&Qs[(qr + l15) * 64 + sw0];
    const bf16x8 bQ1 = *(const bf16x8*)&Qs[(qr + l15) * 64 + sw1];

    const float* mrow = maskl + (size_t)(q0 + qr + l15) * SEQ;

    float m_i = -1e30f, l_i = 0.f;
    f32x4 o4[4];
    #pragma unroll
    for (int mi = 0; mi < 4; mi++) o4[mi] = (f32x4){0.f, 0.f, 0.f, 0.f};

    for (int kt = 0; kt < SEQ / 64; kt++) {
        const int k0 = kt * 64;
        const int cur = kt & 1;

        // mask loads FIRST (oldest in vmcnt FIFO -> waiting on them leaves the
        // prefetch outstanding)
        float4 mv[4];
        #pragma unroll
        for (int ki = 0; ki < 4; ki++)
            mv[ki] = *(const float4*)&mrow[k0 + ki * 16 + l16 * 4];

        // prefetch tile kt+1 into the other buffer (drained by end-of-iter barrier)
        if (kt < SEQ / 64 - 1) {
            const int k1 = k0 + 64, nb = cur ^ 1;
            #pragma unroll
            for (int i = 0; i < 2; i++) {
                const int rg = w * 2 + i;
                gl_lds16(&kh [kbase + (size_t)(k1 + rg * 8 + lr) * DM + gc], &Ks[nb][rg * 512]);
                gl_lds16(&vhT[vbase + (size_t)(rg * 8 + lr) * SEQ + k1 + gc], &Vst[nb][rg * 512]);
            }
        }

        // S^T = K . Q^T : row=key, col=q
        f32x4 s4[4];
        #pragma unroll
        for (int ki = 0; ki < 4; ki++) {
            const int r = ki * 16 + l15;
            const bf16x8 aK0 = *(const bf16x8*)&Ks[cur][r * 64 + sw0];
            const bf16x8 aK1 = *(const bf16x8*)&Ks[cur][r * 64 + sw1];
            f32x4 a0 = (f32x4){0.f, 0.f, 0.f, 0.f};
            a0 = __builtin_amdgcn_mfma_f32_16x16x32_bf16(aK0, bQ0, a0, 0, 0, 0);
            s4[ki] = __builtin_amdgcn_mfma_f32_16x16x32_bf16(aK1, bQ1, a0, 0, 0, 0);
        }

        // sv = s*0.125*log2e + mask*log2e  (log2-domain scores)
        float sv[4][4];
        #pragma unroll
        for (int ki = 0; ki < 4; ki++) {
            sv[ki][0] = s4[ki][0] * SCL + mv[ki].x;
            sv[ki][1] = s4[ki][1] * SCL + mv[ki].y;
            sv[ki][2] = s4[ki][2] * SCL + mv[ki].z;
            sv[ki][3] = s4[ki][3] * SCL + mv[ki].w;
        }

        // online softmax (base-2): lane owns q-row; in-lane reduce + 2 shuffles
        float rm = -1e30f;
        #pragma unroll
        for (int ki = 0; ki < 4; ki++)
            #pragma unroll
            for (int r = 0; r < 4; r++) rm = fmaxf(rm, sv[ki][r]);
        rm = fmaxf(rm, __shfl_xor(rm, 16));
        rm = fmaxf(rm, __shfl_xor(rm, 32));
        const float mnew  = fmaxf(m_i, rm);
        const float alpha = exp2f(m_i - mnew);
        m_i = mnew;

        float ps = 0.f;
        #pragma unroll
        for (int ki = 0; ki < 4; ki++) {
            float p[4];
            #pragma unroll
            for (int r = 0; r < 4; r++) { p[r] = exp2f(sv[ki][r] - mnew); ps += p[r]; }
            uint2 pk;
            pk.x = pack_bf16_trunc(p[0], p[1]);
            pk.y = pack_bf16_trunc(p[2], p[3]);
            *(uint2*)&Ps[(qr + l15) * 72 + ki * 16 + l16 * 4] = pk;
        }
        ps += __shfl_xor(ps, 16);
        ps += __shfl_xor(ps, 32);
        l_i = l_i * alpha + ps;
        #pragma unroll
        for (int mi = 0; mi < 4; mi++)
            #pragma unroll
            for (int r = 0; r < 4; r++) o4[mi][r] *= alpha;

        // O^T += V^T . P^T
        const bf16x8 bP0 = *(const bf16x8*)&Ps[(qr + l15) * 72 + l16 * 8];
        const bf16x8 bP1 = *(const bf16x8*)&Ps[(qr + l15) * 72 + 32 + l16 * 8];
        #pragma unroll
        for (int mi = 0; mi < 4; mi++) {
            const int r = mi * 16 + l15;
            const bf16x8 aV0 = *(const bf16x8*)&Vst[cur][r * 64 + sw0];
            const bf16x8 aV1 = *(const bf16x8*)&Vst[cur][r * 64 + sw1];
            o4[mi] = __builtin_amdgcn_mfma_f32_16x16x32_bf16(aV0, bP0, o4[mi], 0, 0, 0);
            o4[mi] = __builtin_amdgcn_mfma_f32_16x16x32_bf16(aV1, bP1, o4[mi], 0, 0, 0);
        }

        __syncthreads();   // drains prefetch; protects buffers for next iter
    }

    const float inv = 1.f / l_i;
    #pragma unroll
    for (int mi = 0; mi < 4; mi++) {
        ushort4 ok;
        ok.x = f2bf(o4[mi][0] * inv); ok.y = f2bf(o4[mi][1] * inv);
        ok.z = f2bf(o4[mi][2] * inv); ok.w = f2bf(o4[mi][3] * inv);
        *(ushort4*)&z[(size_t)(b * SEQ + q0 + qr + l15) * DM + h * 64 + mi * 16 + l16 * 4] = ok;
    }
}

// ------------------------------------------------------------------
__global__ __launch_bounds__(256) void cast3_bf16(
    const float* __restrict__ a0, const float* __restrict__ a1, const float* __restrict__ a2,
    unsigned short* __restrict__ out)
{
    const float* src = blockIdx.z == 0 ? a0 : (blockIdx.z == 1 ? a1 : a2);
    const size_t i = ((size_t)blockIdx.x * 256 + threadIdx.x) * 4;
    const float4 v = *(const float4*)&src[i];
    ushort4 o; o.x = f2bf(v.x); o.y = f2bf(v.y); o.z = f2bf(v.z); o.w = f2bf(v.w);
    *(ushort4*)&out[(size_t)blockIdx.z * ((size_t)SEQ * 2 * DM) + i] = o;
}

// maskl = mask * log2(e)
__global__ __launch_bounds__(256) void scale_mask(
    const float* __restrict__ m, float* __restrict__ o)
{
    const size_t i = ((size_t)blockIdx.x * 256 + threadIdx.x) * 4;
    float4 v = *(const float4*)&m[i];
    v.x *= 1.44269504f; v.y *= 1.44269504f; v.z *= 1.44269504f; v.w *= 1.44269504f;
    *(float4*)&o[i] = v;
}

// 4x W[1024][1024] fp32 -> Wt[z][1024][1024] bf16 (transposed) ; grid (16,16,4)
__global__ __launch_bounds__(256) void transpose_cast4(
    const float* __restrict__ p0, const float* __restrict__ p1,
    const float* __restrict__ p2, const float* __restrict__ p3,
    unsigned short* __restrict__ Wt)
{
    const float* W = blockIdx.z == 0 ? p0 : (blockIdx.z == 1 ? p1 :
                     (blockIdx.z == 2 ? p2 : p3));
    unsigned short* dst = Wt + (size_t)blockIdx.z * 1024 * 1024;
    __shared__ float ts[64][65];
    const int n0 = blockIdx.x * 64, k0 = blockIdx.y * 64;
    const int t = threadIdx.x, r = t >> 4, c4 = (t & 15) * 4;
    #pragma unroll
    for (int i = 0; i < 4; i++) {
        const float4 v = *(const float4*)&W[(size_t)(k0 + r + i * 16) * 1024 + n0 + c4];
        ts[r + i * 16][c4 + 0] = v.x; ts[r + i * 16][c4 + 1] = v.y;
        ts[r + i * 16][c4 + 2] = v.z; ts[r + i * 16][c4 + 3] = v.w;
    }
    __syncthreads();
    #pragma unroll
    for (int i = 0; i < 4; i++) {
        const int n = r + i * 16;
        ushort4 o;
        o.x = f2bf(ts[c4 + 0][n]); o.y = f2bf(ts[c4 + 1][n]);
        o.z = f2bf(ts[c4 + 2][n]); o.w = f2bf(ts[c4 + 3][n]);
        *(ushort4*)&dst[(size_t)(n0 + n) * 1024 + k0 + c4] = o;
    }
}

// W[K][N] fp32 -> Wt[N][K] bf16 ; grid (N/64, K/64)
__global__ __launch_bounds__(256) void transpose_cast(
    const float* __restrict__ W, unsigned short* __restrict__ Wt, int K, int N)
{
    __shared__ float ts[64][65];
    const int n0 = blockIdx.x * 64, k0 = blockIdx.y * 64;
    const int t = threadIdx.x, r = t >> 4, c4 = (t & 15) * 4;
    #pragma unroll
    for (int i = 0; i < 4; i++) {
        const float4 v = *(const float4*)&W[(size_t)(k0 + r + i * 16) * N + n0 + c4];
        ts[r + i * 16][c4 + 0] = v.x; ts[r + i * 16][c4 + 1] = v.y;
        ts[r + i * 16][c4 + 2] = v.z; ts[r + i * 16][c4 + 3] = v.w;
    }
    __syncthreads();
    #pragma unroll
    for (int i = 0; i < 4; i++) {
        const int n = r + i * 16;
        ushort4 o;
        o.x = f2bf(ts[c4 + 0][n]); o.y = f2bf(ts[c4 + 1][n]);
        o.z = f2bf(ts[c4 + 2][n]); o.w = f2bf(ts[c4 + 3][n]);
        *(ushort4*)&Wt[(size_t)(n0 + n) * K + k0 + c4] = o;
    }
}

// vh bf16 [B*S][DM] -> vhT bf16 [(b*16+h)*64 + d][SEQ] ; grid (S/64, H, B)
__global__ __launch_bounds__(256) void transpose_v(
    const unsigned short* __restrict__ vh, unsigned short* __restrict__ vhT)
{
    __shared__ unsigned short ts[64][80];
    const int s0 = blockIdx.x * 64, h = blockIdx.y, b = blockIdx.z;
    const int t = threadIdx.x, rr = t >> 3, c8 = (t & 7) * 8;
    #pragma unroll
    for (int i = 0; i < 2; i++) {
        const int srow = rr + i * 32;
        *(uint4*)&ts[srow][c8] = *(const uint4*)&vh[(size_t)(b * SEQ + s0 + srow) * DM + h * 64 + c8];
    }
    __syncthreads();
    #pragma unroll
    for (int i = 0; i < 2; i++) {
        const int dr = rr + i * 32;
        ushort4 ov0, ov1;
        ov0.x = ts[c8 + 0][dr]; ov0.y = ts[c8 + 1][dr];
        ov0.z = ts[c8 + 2][dr]; ov0.w = ts[c8 + 3][dr];
        ov1.x = ts[c8 + 4][dr]; ov1.y = ts[c8 + 5][dr];
        ov1.z = ts[c8 + 6][dr]; ov1.w = ts[c8 + 7][dr];
        *(ushort4*)&vhT[(size_t)((b * 16 + h) * 64 + dr) * SEQ + s0 + c8] = ov0;
        *(ushort4*)&vhT[(size_t)((b * 16 + h) * 64 + dr) * SEQ + s0 + c8 + 4] = ov1;
    }
}

// ------------------------------------------------------------------
// LN + residual with optional second partial input (split-K sum).
// mode 0: out = LN(a+a2)*g+be + r (+bf16 copy) ; mode 1: out = LN(a+a2+r)*g+be
// ------------------------------------------------------------------
__global__ __launch_bounds__(256) void ln_res(
    const float* __restrict__ a, const float* __restrict__ a2,
    const float* __restrict__ r,
    const float* __restrict__ g, const float* __restrict__ be,
    float* __restrict__ out, unsigned short* __restrict__ outb, int mode)
{
    __shared__ float redls[8];
    const int row = blockIdx.x, t = threadIdx.x;
    const size_t base = (size_t)row * DM;

    float vals[4], s = 0.f, sq = 0.f;
    #pragma unroll
    for (int i = 0; i < 4; i++) {
        const int c = t + 256 * i;
        float x = a[base + c];
        if (a2) x += a2[base + c];
        if (mode == 1) x += r[base + c];
        vals[i] = x; s += x; sq += x * x;
    }
    #pragma unroll
    for (int off = 32; off > 0; off >>= 1) { s += __shfl_down(s, off); sq += __shfl_down(sq, off); }
    if ((t & 63) == 0) { redls[t >> 6] = s; redls[4 + (t >> 6)] = sq; }
    __syncthreads();
    s  = redls[0] + redls[1] + redls[2] + redls[3];
    sq = redls[4] + redls[5] + redls[6] + redls[7];

    const float mu  = s * (1.f / 1024.f);
    const float var = sq * (1.f / 1024.f) - mu * mu;
    const float rs  = rsqrtf(var + LNEPS);
    #pragma unroll
    for (int i = 0; i < 4; i++) {
        const int c = t + 256 * i;
        float y = (vals[i] - mu) * rs * g[c] + be[c];
        if (mode == 0) y += r[base + c];
        out[base + c] = y;
        if (outb) outb[base + c] = f2bf(y);
    }
}

// ------------------------------------------------------------------
extern "C" void kernel_launch(void* const* d_in, const int* in_sizes, int n_in,
                              void* d_out, int out_size, void* d_ws, size_t ws_size,
                              hipStream_t stream)
{
    const float* q    = (const float*)d_in[0];
    const float* k    = (const float*)d_in[1];
    const float* v    = (const float*)d_in[2];
    const float* mask = (const float*)d_in[4];
    const float* Wq   = (const float*)d_in[5];
    const float* Wk   = (const float*)d_in[6];
    const float* Wv   = (const float*)d_in[7];
    const float* Wd   = (const float*)d_in[8];
    const float* W1   = (const float*)d_in[9];
    const float* b1   = (const float*)d_in[10];
    const float* W2   = (const float*)d_in[11];
    const float* b2   = (const float*)d_in[12];
    const float* g1   = (const float*)d_in[13];
    const float* be1  = (const float*)d_in[14];
    const float* g2   = (const float*)d_in[15];
    const float* be2  = (const float*)d_in[16];
    float* out = (float*)d_out;

    char* WS = (char*)d_ws;
    const size_t MiB = 1u << 20;
    const size_t ND  = (size_t)4096 * 1024;

    unsigned short* qb  = (unsigned short*)(WS + 0);          // 24 MiB qb|kb|vb
    unsigned short* vhT = (unsigned short*)(WS + 0);          //  8 MiB (reuse)
    unsigned short* zb  = (unsigned short*)(WS + 8 * MiB);    //  8 MiB (reuse)
    unsigned short* xb  = (unsigned short*)(WS + 16 * MiB);   //  8 MiB (reuse)
    unsigned short* Wqt = (unsigned short*)(WS + 24 * MiB);   //  8 MiB WqT|WkT|WvT|WdT
    unsigned short* W1t = (unsigned short*)(WS + 32 * MiB);   //  8 MiB
    unsigned short* W2t = (unsigned short*)(WS + 40 * MiB);   //  8 MiB
    unsigned short* qh  = (unsigned short*)(WS + 48 * MiB);   // 24 MiB qh|kh|vh
    float*          zd0 = (float*)(WS + 48 * MiB);            // 16 MiB (reuse qh|kh)
    float*          zd1 = (float*)(WS + 64 * MiB);            // 16 MiB (reuse vh+)
    float*          x   = (float*)(WS + 80 * MiB);            // 16 MiB
    unsigned short* h1  = (unsigned short*)(WS + 96 * MiB);   // 32 MiB
    float*          mkl = (float*)(WS + 96 * MiB);            // 16 MiB (dead until FF1)
    float*          y0  = (float*)(WS + 48 * MiB);            // reuse zd
    float*          y1  = (float*)(WS + 64 * MiB);

    unsigned short* kh  = qh + ND;
    unsigned short* vh  = qh + 2 * ND;
    unsigned short* Wdt = Wqt + 3 * 1024 * 1024;

    const dim3 blk(256);

    cast3_bf16<<<dim3(4096, 1, 3), blk, 0, stream>>>(q, k, v, qb);
    scale_mask<<<dim3(4096), blk, 0, stream>>>(mask, mkl);
    transpose_cast4<<<dim3(16, 16, 4), blk, 0, stream>>>(Wq, Wk, Wv, Wd, Wqt);
    transpose_cast<<<dim3(64, 16), blk, 0, stream>>>(W1, W1t, 1024, 4096);
    transpose_cast<<<dim3(16, 64), blk, 0, stream>>>(W2, W2t, 4096, 1024);

    // QKV projections (z = batch of 3)
    gemm_bf16<<<dim3(8, 32, 3), blk, 0, stream>>>(qb, Wqt, nullptr, qh,
        4096, 1024, 1024, 1024, 1024, ND, (size_t)1024 * 1024, ND, nullptr, 0);

    transpose_v<<<dim3(32, 16, 2), blk, 0, stream>>>(vh, vhT);

    attn_mfma<<<dim3(1024), blk, 0, stream>>>(qh, kh, vhT, mkl, zb);

    // out-proj, split-K x2 -> zd0/zd1
    gemm_bf16<<<dim3(8, 32, 2), blk, 0, stream>>>(zb, Wdt, zd0, nullptr,
        4096, 1024, 512, 1024, 1024, 512, 512, ND, nullptr, 0);

    // LN1: x = LN(zd0+zd1) + q
    ln_res<<<dim3(4096), blk, 0, stream>>>(zd0, zd1, q, g1, be1, x, xb, 0);

    // FFN
    gemm_bf16<<<dim3(32, 32, 1), blk, 0, stream>>>(xb, W1t, nullptr, h1,
        4096, 4096, 1024, 1024, 1024, 0, 0, 0, b1, 2);
    gemm_bf16<<<dim3(8, 32, 2), blk, 0, stream>>>(h1, W2t, y0, nullptr,
        4096, 1024, 2048, 4096, 4096, 2048, 2048, ND, b2, 1);

    // LN2: out = LN(y0+y1+x)
    ln_res<<<dim3(4096), blk, 0, stream>>>(y0, y1, x, g2, be2, out, nullptr, 1);
}

// Round 7
// 533.151 us; speedup vs baseline: 1.0097x; 1.0097x over previous
//
#include <hip/hip_runtime.h>
#include <hip/hip_bf16.h>

// EncoderCell, bf16-MFMA, round 7 (= round 6 + LDS merge-scratch overflow fix).
//   attn_mfma: one wave = 64 q-rows x half key range; K/V/Q/mask fragments
//              loaded directly global->register; only P round-trips
//              wave-private LDS; no __syncthreads in K-loop; K-split x2 with
//              end merge via LDS (per-wave region 5632 shorts: P [0,4608),
//              merge O [0,4096) + m/l floats at short 4608..5632).
//   V-projection computed pre-transposed (C' = WvT . v^T).
// ws (MiB): [0,8) qb->vhT ; [8,16) kb->zb ; [16,24) vb->xb ; [24,32) WqkvdT ;
//   [32,40) W1T ; [40,48) W2T ; [48,64) qh|kh -> zd0/y0 ; [64,80) zd1/y1 ;
//   [80,96) x ; [96,104) mb (dead at FF1) ; [96,128) h1. = 128 MiB.

#define SEQ 2048
#define DM  1024
#define LNEPS 1e-5f
#define SCL  0.1803368801f   // 0.125 * log2(e)
#define PW   5632            // per-wave LDS region, shorts

typedef __attribute__((ext_vector_type(8))) short bf16x8;
typedef __attribute__((ext_vector_type(4))) float f32x4;

#define GAS __attribute__((address_space(1)))
#define LAS __attribute__((address_space(3)))

static __device__ __forceinline__ void gl_lds16(const unsigned short* g, unsigned short* l) {
    __builtin_amdgcn_global_load_lds((const GAS void*)g, (LAS void*)l, 16, 0, 0);
}

static __device__ __forceinline__ unsigned short f2bf(float f) {
    unsigned u = __builtin_bit_cast(unsigned, f);
    u += 0x7fffu + ((u >> 16) & 1u);   // RNE
    return (unsigned short)(u >> 16);
}

static __device__ __forceinline__ float bf2f(unsigned short s) {
    return __builtin_bit_cast(float, (unsigned)s << 16);
}

// pack two fp32 -> two bf16 (truncation) in one v_perm_b32
static __device__ __forceinline__ unsigned pack_bf16_trunc(float a, float b) {
    return __builtin_amdgcn_perm(__builtin_bit_cast(unsigned, b),
                                 __builtin_bit_cast(unsigned, a), 0x07060302u);
}

// ------------------------------------------------------------------
// C[M,N] (per-z slice) = A[M,Klen] @ Bt[N,Klen]^T. bias only on z==0.
// ------------------------------------------------------------------
__global__ __launch_bounds__(256) void gemm_bf16(
    const unsigned short* __restrict__ A, const unsigned short* __restrict__ Bt,
    float* __restrict__ Cf, unsigned short* __restrict__ Cb,
    int M, int N, int Klen, int lda, int ldb,
    size_t sA, size_t sB, size_t sC,
    const float* __restrict__ bias, int ep)
{
    __shared__ unsigned short As[128 * 32];
    __shared__ unsigned short Bs[128 * 32];

    const int t = threadIdx.x, lane = t & 63, w = t >> 6;
    const int wm = w >> 1, wn = w & 1;
    const int m0 = blockIdx.y * 128, n0 = blockIdx.x * 128;
    A  += (size_t)blockIdx.z * sA;
    Bt += (size_t)blockIdx.z * sB;
    const size_t cbase = (size_t)blockIdx.z * sC;
    const int l15 = lane & 15, l16 = lane >> 4;
    const int ar = lane >> 2, ac = (lane & 3) * 8;

    f32x4 acc[4][4];
    #pragma unroll
    for (int i = 0; i < 4; i++)
        #pragma unroll
        for (int j = 0; j < 4; j++)
            acc[i][j] = (f32x4){0.f, 0.f, 0.f, 0.f};

    for (int k0 = 0; k0 < Klen; k0 += 32) {
        __syncthreads();
        #pragma unroll
        for (int i = 0; i < 2; i++) {
            const int rg = w * 2 + i;
            gl_lds16(&A [(size_t)(m0 + rg * 16 + ar) * lda + k0 + ac], &As[rg * 512]);
            gl_lds16(&Bt[(size_t)(n0 + rg * 16 + ar) * ldb + k0 + ac], &Bs[rg * 512]);
        }
        __syncthreads();

        bf16x8 af[4], bfr[4];
        #pragma unroll
        for (int i = 0; i < 4; i++) {
            af[i]  = *(const bf16x8*)&As[(wm * 64 + i * 16 + l15) * 32 + l16 * 8];
            bfr[i] = *(const bf16x8*)&Bs[(wn * 64 + i * 16 + l15) * 32 + l16 * 8];
        }
        #pragma unroll
        for (int mi = 0; mi < 4; mi++)
            #pragma unroll
            for (int ni = 0; ni < 4; ni++)
                acc[mi][ni] = __builtin_amdgcn_mfma_f32_16x16x32_bf16(
                    af[mi], bfr[ni], acc[mi][ni], 0, 0, 0);
    }

    #pragma unroll
    for (int ni = 0; ni < 4; ni++) {
        const int col = n0 + wn * 64 + ni * 16 + l15;
        const float bv = (ep && blockIdx.z == 0) ? bias[col] : 0.f;
        #pragma unroll
        for (int mi = 0; mi < 4; mi++) {
            #pragma unroll
            for (int r = 0; r < 4; r++) {
                const int row = m0 + wm * 64 + mi * 16 + l16 * 4 + r;
                float vv = acc[mi][ni][r] + bv;
                if (ep == 2) vv = fmaxf(vv, 0.f);
                if (Cf) Cf[cbase + (size_t)row * N + col] = vv;
                else    Cb[cbase + (size_t)row * N + col] = f2bf(vv);
            }
        }
    }
}

// ------------------------------------------------------------------
// Flash attention: wave-independent, direct global->register fragments.
// grid = 512 blocks x 256 thr = 2048 waves. Wave W = bid*4+w:
//   pair P = W>>1: qt = P&31, h = (P>>5)&15, b = P>>9 ; ks = W&1 (key half).
// Wave computes 64 q-rows (q0=qt*64) over keys [ks*1024, ks*1024+1024).
// Partner waves (w, w^1) merge (m,l,O) at the end via LDS + one barrier.
// vhT is [1024][4096]: row = h*64+d, col = b*2048 + s.
// ------------------------------------------------------------------
__global__ __launch_bounds__(256, 2) void attn_mfma(
    const unsigned short* __restrict__ qh, const unsigned short* __restrict__ kh,
    const unsigned short* __restrict__ vhT, const unsigned short* __restrict__ mb,
    unsigned short* __restrict__ z)
{
    __shared__ unsigned short Ps[4][PW];   // per-wave: P tile / merge scratch

    const int t = threadIdx.x, lane = t & 63, w = t >> 6;
    const int W = blockIdx.x * 4 + w;
    const int P = W >> 1, ks = W & 1;
    const int qt = P & 31, h = (P >> 5) & 15, b = P >> 9;
    const int q0 = qt * 64;
    const int l15 = lane & 15, l16 = lane >> 4;
    unsigned short* ps = &Ps[w][0];

    const size_t qrow = (size_t)(b * SEQ + q0);
    const size_t krow = (size_t)(b * SEQ);
    const size_t vrow = (size_t)(h * 64);        // + d ; col stride 4096
    const int    vcol = b * SEQ;

    // Q B-fragments, persistent: bQ[qi][half]
    bf16x8 bQ[4][2];
    #pragma unroll
    for (int qi = 0; qi < 4; qi++)
        #pragma unroll
        for (int hf = 0; hf < 2; hf++)
            bQ[qi][hf] = *(const bf16x8*)&qh[(qrow + qi * 16 + l15) * DM + h * 64 + hf * 32 + l16 * 8];

    float m_i[4], l_i[4];
    f32x4 o4[4][4];                               // [mi(d)][qi]
    #pragma unroll
    for (int qi = 0; qi < 4; qi++) { m_i[qi] = -1e30f; l_i[qi] = 0.f; }
    #pragma unroll
    for (int mi = 0; mi < 4; mi++)
        #pragma unroll
        for (int qi = 0; qi < 4; qi++)
            o4[mi][qi] = (f32x4){0.f, 0.f, 0.f, 0.f};

    const int kt0 = ks * 16;
    for (int kt = kt0; kt < kt0 + 16; kt++) {
        const int k0 = kt * 64;

        // K A-fragments for this tile: aK[ki][half]
        bf16x8 aK[4][2];
        #pragma unroll
        for (int ki = 0; ki < 4; ki++)
            #pragma unroll
            for (int hf = 0; hf < 2; hf++)
                aK[ki][hf] = *(const bf16x8*)&kh[(krow + k0 + ki * 16 + l15) * DM + h * 64 + hf * 32 + l16 * 8];

        float alpha[4];
        #pragma unroll
        for (int qi = 0; qi < 4; qi++) {
            // mask (bf16): keys ki*16 + l16*4 + r for q-row qi*16+l15
            ushort4 mu[4];
            #pragma unroll
            for (int ki = 0; ki < 4; ki++)
                mu[ki] = *(const ushort4*)&mb[(size_t)(q0 + qi * 16 + l15) * SEQ + k0 + ki * 16 + l16 * 4];

            f32x4 s4[4];
            #pragma unroll
            for (int ki = 0; ki < 4; ki++) {
                f32x4 a0 = (f32x4){0.f, 0.f, 0.f, 0.f};
                a0 = __builtin_amdgcn_mfma_f32_16x16x32_bf16(aK[ki][0], bQ[qi][0], a0, 0, 0, 0);
                s4[ki] = __builtin_amdgcn_mfma_f32_16x16x32_bf16(aK[ki][1], bQ[qi][1], a0, 0, 0, 0);
            }

            float sv[4][4];
            #pragma unroll
            for (int ki = 0; ki < 4; ki++) {
                sv[ki][0] = s4[ki][0] * SCL + bf2f(mu[ki].x) * 1.44269504f;
                sv[ki][1] = s4[ki][1] * SCL + bf2f(mu[ki].y) * 1.44269504f;
                sv[ki][2] = s4[ki][2] * SCL + bf2f(mu[ki].z) * 1.44269504f;
                sv[ki][3] = s4[ki][3] * SCL + bf2f(mu[ki].w) * 1.44269504f;
            }

            float rm = -1e30f;
            #pragma unroll
            for (int ki = 0; ki < 4; ki++)
                #pragma unroll
                for (int r = 0; r < 4; r++) rm = fmaxf(rm, sv[ki][r]);
            rm = fmaxf(rm, __shfl_xor(rm, 16));
            rm = fmaxf(rm, __shfl_xor(rm, 32));
            const float mnew = fmaxf(m_i[qi], rm);
            alpha[qi] = exp2f(m_i[qi] - mnew);
            m_i[qi] = mnew;

            float pssum = 0.f;
            #pragma unroll
            for (int ki = 0; ki < 4; ki++) {
                float p[4];
                #pragma unroll
                for (int r = 0; r < 4; r++) { p[r] = exp2f(sv[ki][r] - mnew); pssum += p[r]; }
                uint2 pk;
                pk.x = pack_bf16_trunc(p[0], p[1]);
                pk.y = pack_bf16_trunc(p[2], p[3]);
                *(uint2*)&ps[(qi * 16 + l15) * 72 + ki * 16 + l16 * 4] = pk;
            }
            pssum += __shfl_xor(pssum, 16);
            pssum += __shfl_xor(pssum, 32);
            l_i[qi] = l_i[qi] * alpha[qi] + pssum;
        }

        // rescale O
        #pragma unroll
        for (int mi = 0; mi < 4; mi++)
            #pragma unroll
            for (int qi = 0; qi < 4; qi++)
                #pragma unroll
                for (int r = 0; r < 4; r++) o4[mi][qi][r] *= alpha[qi];

        // V A-fragments: aV[mi][half] (V^T [d][key])
        bf16x8 aV[4][2];
        #pragma unroll
        for (int mi = 0; mi < 4; mi++)
            #pragma unroll
            for (int hf = 0; hf < 2; hf++)
                aV[mi][hf] = *(const bf16x8*)&vhT[(vrow + mi * 16 + l15) * 4096 + vcol + k0 + hf * 32 + l16 * 8];

        // P B-fragments from wave-private LDS
        bf16x8 bP[4][2];
        #pragma unroll
        for (int qi = 0; qi < 4; qi++)
            #pragma unroll
            for (int hf = 0; hf < 2; hf++)
                bP[qi][hf] = *(const bf16x8*)&ps[(qi * 16 + l15) * 72 + hf * 32 + l16 * 8];

        #pragma unroll
        for (int mi = 0; mi < 4; mi++)
            #pragma unroll
            for (int qi = 0; qi < 4; qi++) {
                o4[mi][qi] = __builtin_amdgcn_mfma_f32_16x16x32_bf16(aV[mi][0], bP[qi][0], o4[mi][qi], 0, 0, 0);
                o4[mi][qi] = __builtin_amdgcn_mfma_f32_16x16x32_bf16(aV[mi][1], bP[qi][1], o4[mi][qi], 0, 0, 0);
            }
    }

    // ---- merge partner halves (w, w^1) ----
    // own scratch: O tile (bf16) at [0,4096), m/l floats at shorts [4608,5632).
    #pragma unroll
    for (int mi = 0; mi < 4; mi++)
        #pragma unroll
        for (int qi = 0; qi < 4; qi++) {
            uint2 pk;
            pk.x = pack_bf16_trunc(o4[mi][qi][0], o4[mi][qi][1]);
            pk.y = pack_bf16_trunc(o4[mi][qi][2], o4[mi][qi][3]);
            *(uint2*)&ps[(mi * 4 + qi) * 256 + lane * 4] = pk;
        }
    float* fml = (float*)&ps[4608];   // 512 floats = 1024 shorts, fits in PW
    #pragma unroll
    for (int qi = 0; qi < 4; qi++) {
        fml[lane * 8 + qi] = m_i[qi];
        fml[lane * 8 + 4 + qi] = l_i[qi];
    }
    __syncthreads();

    if (ks == 0) {
        const unsigned short* pp = &Ps[w ^ 1][0];
        const float* pml = (const float*)&pp[4608];
        float inv[4], a1[4], a2[4];
        #pragma unroll
        for (int qi = 0; qi < 4; qi++) {
            const float m2 = pml[lane * 8 + qi];
            const float l2 = pml[lane * 8 + 4 + qi];
            const float mM = fmaxf(m_i[qi], m2);
            a1[qi] = exp2f(m_i[qi] - mM);
            a2[qi] = exp2f(m2 - mM);
            inv[qi] = 1.f / (a1[qi] * l_i[qi] + a2[qi] * l2);
        }
        #pragma unroll
        for (int mi = 0; mi < 4; mi++)
            #pragma unroll
            for (int qi = 0; qi < 4; qi++) {
                const ushort4 ov = *(const ushort4*)&pp[(mi * 4 + qi) * 256 + lane * 4];
                ushort4 ok;
                ok.x = f2bf((o4[mi][qi][0] * a1[qi] + bf2f(ov.x) * a2[qi]) * inv[qi]);
                ok.y = f2bf((o4[mi][qi][1] * a1[qi] + bf2f(ov.y) * a2[qi]) * inv[qi]);
                ok.z = f2bf((o4[mi][qi][2] * a1[qi] + bf2f(ov.z) * a2[qi]) * inv[qi]);
                ok.w = f2bf((o4[mi][qi][3] * a1[qi] + bf2f(ov.w) * a2[qi]) * inv[qi]);
                *(ushort4*)&z[(qrow + qi * 16 + l15) * DM + h * 64 + mi * 16 + l16 * 4] = ok;
            }
    }
}

// ------------------------------------------------------------------
__global__ __launch_bounds__(256) void cast3_bf16(
    const float* __restrict__ a0, const float* __restrict__ a1, const float* __restrict__ a2,
    unsigned short* __restrict__ out)
{
    const float* src = blockIdx.z == 0 ? a0 : (blockIdx.z == 1 ? a1 : a2);
    const size_t i = ((size_t)blockIdx.x * 256 + threadIdx.x) * 4;
    const float4 v = *(const float4*)&src[i];
    ushort4 o; o.x = f2bf(v.x); o.y = f2bf(v.y); o.z = f2bf(v.z); o.w = f2bf(v.w);
    *(ushort4*)&out[(size_t)blockIdx.z * ((size_t)SEQ * 2 * DM) + i] = o;
}

// mask fp32 -> bf16
__global__ __launch_bounds__(256) void mask_bf16(
    const float* __restrict__ m, unsigned short* __restrict__ o)
{
    const size_t i = ((size_t)blockIdx.x * 256 + threadIdx.x) * 4;
    const float4 v = *(const float4*)&m[i];
    ushort4 u; u.x = f2bf(v.x); u.y = f2bf(v.y); u.z = f2bf(v.z); u.w = f2bf(v.w);
    *(ushort4*)&o[i] = u;
}

// 4x W[1024][1024] fp32 -> Wt[z][1024][1024] bf16 (transposed) ; grid (16,16,4)
__global__ __launch_bounds__(256) void transpose_cast4(
    const float* __restrict__ p0, const float* __restrict__ p1,
    const float* __restrict__ p2, const float* __restrict__ p3,
    unsigned short* __restrict__ Wt)
{
    const float* W = blockIdx.z == 0 ? p0 : (blockIdx.z == 1 ? p1 :
                     (blockIdx.z == 2 ? p2 : p3));
    unsigned short* dst = Wt + (size_t)blockIdx.z * 1024 * 1024;
    __shared__ float ts[64][65];
    const int n0 = blockIdx.x * 64, k0 = blockIdx.y * 64;
    const int t = threadIdx.x, r = t >> 4, c4 = (t & 15) * 4;
    #pragma unroll
    for (int i = 0; i < 4; i++) {
        const float4 v = *(const float4*)&W[(size_t)(k0 + r + i * 16) * 1024 + n0 + c4];
        ts[r + i * 16][c4 + 0] = v.x; ts[r + i * 16][c4 + 1] = v.y;
        ts[r + i * 16][c4 + 2] = v.z; ts[r + i * 16][c4 + 3] = v.w;
    }
    __syncthreads();
    #pragma unroll
    for (int i = 0; i < 4; i++) {
        const int n = r + i * 16;
        ushort4 o;
        o.x = f2bf(ts[c4 + 0][n]); o.y = f2bf(ts[c4 + 1][n]);
        o.z = f2bf(ts[c4 + 2][n]); o.w = f2bf(ts[c4 + 3][n]);
        *(ushort4*)&dst[(size_t)(n0 + n) * 1024 + k0 + c4] = o;
    }
}

// W[K][N] fp32 -> Wt[N][K] bf16 ; grid (N/64, K/64)
__global__ __launch_bounds__(256) void transpose_cast(
    const float* __restrict__ W, unsigned short* __restrict__ Wt, int K, int N)
{
    __shared__ float ts[64][65];
    const int n0 = blockIdx.x * 64, k0 = blockIdx.y * 64;
    const int t = threadIdx.x, r = t >> 4, c4 = (t & 15) * 4;
    #pragma unroll
    for (int i = 0; i < 4; i++) {
        const float4 v = *(const float4*)&W[(size_t)(k0 + r + i * 16) * N + n0 + c4];
        ts[r + i * 16][c4 + 0] = v.x; ts[r + i * 16][c4 + 1] = v.y;
        ts[r + i * 16][c4 + 2] = v.z; ts[r + i * 16][c4 + 3] = v.w;
    }
    __syncthreads();
    #pragma unroll
    for (int i = 0; i < 4; i++) {
        const int n = r + i * 16;
        ushort4 o;
        o.x = f2bf(ts[c4 + 0][n]); o.y = f2bf(ts[c4 + 1][n]);
        o.z = f2bf(ts[c4 + 2][n]); o.w = f2bf(ts[c4 + 3][n]);
        *(ushort4*)&Wt[(size_t)(n0 + n) * K + k0 + c4] = o;
    }
}

// ------------------------------------------------------------------
// LN + residual with optional second partial input (split-K sum).
// mode 0: out = LN(a+a2)*g+be + r (+bf16 copy) ; mode 1: out = LN(a+a2+r)*g+be
// ------------------------------------------------------------------
__global__ __launch_bounds__(256) void ln_res(
    const float* __restrict__ a, const float* __restrict__ a2,
    const float* __restrict__ r,
    const float* __restrict__ g, const float* __restrict__ be,
    float* __restrict__ out, unsigned short* __restrict__ outb, int mode)
{
    __shared__ float redls[8];
    const int row = blockIdx.x, t = threadIdx.x;
    const size_t base = (size_t)row * DM;

    float vals[4], s = 0.f, sq = 0.f;
    #pragma unroll
    for (int i = 0; i < 4; i++) {
        const int c = t + 256 * i;
        float x = a[base + c];
        if (a2) x += a2[base + c];
        if (mode == 1) x += r[base + c];
        vals[i] = x; s += x; sq += x * x;
    }
    #pragma unroll
    for (int off = 32; off > 0; off >>= 1) { s += __shfl_down(s, off); sq += __shfl_down(sq, off); }
    if ((t & 63) == 0) { redls[t >> 6] = s; redls[4 + (t >> 6)] = sq; }
    __syncthreads();
    s  = redls[0] + redls[1] + redls[2] + redls[3];
    sq = redls[4] + redls[5] + redls[6] + redls[7];

    const float mu  = s * (1.f / 1024.f);
    const float var = sq * (1.f / 1024.f) - mu * mu;
    const float rs  = rsqrtf(var + LNEPS);
    #pragma unroll
    for (int i = 0; i < 4; i++) {
        const int c = t + 256 * i;
        float y = (vals[i] - mu) * rs * g[c] + be[c];
        if (mode == 0) y += r[base + c];
        out[base + c] = y;
        if (outb) outb[base + c] = f2bf(y);
    }
}

// ------------------------------------------------------------------
extern "C" void kernel_launch(void* const* d_in, const int* in_sizes, int n_in,
                              void* d_out, int out_size, void* d_ws, size_t ws_size,
                              hipStream_t stream)
{
    const float* q    = (const float*)d_in[0];
    const float* k    = (const float*)d_in[1];
    const float* v    = (const float*)d_in[2];
    const float* mask = (const float*)d_in[4];
    const float* Wq   = (const float*)d_in[5];
    const float* Wk   = (const float*)d_in[6];
    const float* Wv   = (const float*)d_in[7];
    const float* Wd   = (const float*)d_in[8];
    const float* W1   = (const float*)d_in[9];
    const float* b1   = (const float*)d_in[10];
    const float* W2   = (const float*)d_in[11];
    const float* b2   = (const float*)d_in[12];
    const float* g1   = (const float*)d_in[13];
    const float* be1  = (const float*)d_in[14];
    const float* g2   = (const float*)d_in[15];
    const float* be2  = (const float*)d_in[16];
    float* out = (float*)d_out;

    char* WS = (char*)d_ws;
    const size_t MiB = 1u << 20;
    const size_t ND  = (size_t)4096 * 1024;

    unsigned short* qb  = (unsigned short*)(WS + 0);          //  8 MiB
    unsigned short* vhT = (unsigned short*)(WS + 0);          //  8 MiB (reuse qb)
    unsigned short* zb  = (unsigned short*)(WS + 8 * MiB);    //  8 MiB (reuse kb)
    unsigned short* xb  = (unsigned short*)(WS + 16 * MiB);   //  8 MiB (reuse vb)
    unsigned short* Wqt = (unsigned short*)(WS + 24 * MiB);   //  8 MiB WqT|WkT|WvT|WdT
    unsigned short* W1t = (unsigned short*)(WS + 32 * MiB);   //  8 MiB
    unsigned short* W2t = (unsigned short*)(WS + 40 * MiB);   //  8 MiB
    unsigned short* qh  = (unsigned short*)(WS + 48 * MiB);   // 16 MiB qh|kh
    float*          zd0 = (float*)(WS + 48 * MiB);            // 16 MiB (reuse qh|kh)
    float*          zd1 = (float*)(WS + 64 * MiB);            // 16 MiB
    float*          x   = (float*)(WS + 80 * MiB);            // 16 MiB
    unsigned short* mb  = (unsigned short*)(WS + 96 * MiB);   //  8 MiB (dead at FF1)
    unsigned short* h1  = (unsigned short*)(WS + 96 * MiB);   // 32 MiB
    float*          y0  = (float*)(WS + 48 * MiB);
    float*          y1  = (float*)(WS + 64 * MiB);

    unsigned short* kb  = qb + ND;      // [8,16)
    unsigned short* vb  = qb + 2 * ND;  // [16,24)
    unsigned short* kh  = qh + ND;
    unsigned short* WvT = Wqt + 2 * 1024 * 1024;
    unsigned short* Wdt = Wqt + 3 * 1024 * 1024;

    const dim3 blk(256);

    cast3_bf16<<<dim3(4096, 1, 3), blk, 0, stream>>>(q, k, v, qb);
    mask_bf16<<<dim3(4096), blk, 0, stream>>>(mask, mb);
    transpose_cast4<<<dim3(16, 16, 4), blk, 0, stream>>>(Wq, Wk, Wv, Wd, Wqt);
    transpose_cast<<<dim3(64, 16), blk, 0, stream>>>(W1, W1t, 1024, 4096);
    transpose_cast<<<dim3(16, 64), blk, 0, stream>>>(W2, W2t, 4096, 1024);

    // Q,K projections (z = batch of 2) -> qh, kh
    gemm_bf16<<<dim3(8, 32, 2), blk, 0, stream>>>(qb, Wqt, nullptr, qh,
        4096, 1024, 1024, 1024, 1024, ND, (size_t)1024 * 1024, ND, nullptr, 0);

    // V projection, pre-transposed: vhT[1024][4096] = WvT . vb^T (overwrites qb)
    gemm_bf16<<<dim3(32, 8, 1), blk, 0, stream>>>(WvT, vb, nullptr, vhT,
        1024, 4096, 1024, 1024, 1024, 0, 0, 0, nullptr, 0);

    attn_mfma<<<dim3(512), blk, 0, stream>>>(qh, kh, vhT, mb, zb);

    // out-proj, split-K x2 -> zd0/zd1
    gemm_bf16<<<dim3(8, 32, 2), blk, 0, stream>>>(zb, Wdt, zd0, nullptr,
        4096, 1024, 512, 1024, 1024, 512, 512, ND, nullptr, 0);

    // LN1: x = LN(zd0+zd1) + q
    ln_res<<<dim3(4096), blk, 0, stream>>>(zd0, zd1, q, g1, be1, x, xb, 0);

    // FFN
    gemm_bf16<<<dim3(32, 32, 1), blk, 0, stream>>>(xb, W1t, nullptr, h1,
        4096, 4096, 1024, 1024, 1024, 0, 0, 0, b1, 2);
    gemm_bf16<<<dim3(8, 32, 2), blk, 0, stream>>>(h1, W2t, y0, nullptr,
        4096, 1024, 2048, 4096, 4096, 2048, 2048, ND, b2, 1);

    // LN2: out = LN(y0+y1+x)
    ln_res<<<dim3(4096), blk, 0, stream>>>(y0, y1, x, g2, be2, out, nullptr, 1);
}